// Round 1
// baseline (672.089 us; speedup 1.0000x reference)
//
#include <hip/hip_runtime.h>
#include <math.h>

// Workspace layout (floats):
//  pT0 [4][128][36]   @ OFF0
//  pT1 [4][128][128]  @ OFF1
//  pT2 [4][128][128]  @ OFF2
//  pT3 [4][128][128]  @ OFF3
//  pT4 [4][2][128]    @ OFF4
//  bias[5][4][128]    @ OFFB   (layer-major; L4 uses o=0,1)
// total 218624 floats = 874496 bytes (ws must be >= this)
#define OFF0 0
#define OFF1 18432
#define OFF2 83968
#define OFF3 149504
#define OFF4 215040
#define OFFB 216064

__global__ void prep_params(
    const float* __restrict__ w0, const float* __restrict__ w1,
    const float* __restrict__ w2, const float* __restrict__ w3,
    const float* __restrict__ w4,
    const float* __restrict__ m0, const float* __restrict__ m1,
    const float* __restrict__ m2, const float* __restrict__ m3,
    const float* __restrict__ m4,
    float* __restrict__ ws)
{
    int idx = blockIdx.x * blockDim.x + threadIdx.x;
    if (idx >= 2056) return;
    int layer, b, o;
    if (idx < 2048) { layer = idx >> 9; b = (idx >> 7) & 3; o = idx & 127; }
    else { layer = 4; int r = idx - 2048; b = r >> 1; o = r & 1; }

    const float* w; const float* m; int Fm, O, Fp; int off;
    switch (layer) {
      case 0:  w = w0; m = m0; Fm = 35;  O = 128; Fp = 36;  off = OFF0; break;
      case 1:  w = w1; m = m1; Fm = 128; O = 128; Fp = 128; off = OFF1; break;
      case 2:  w = w2; m = m2; Fm = 128; O = 128; Fp = 128; off = OFF2; break;
      case 3:  w = w3; m = m3; Fm = 128; O = 128; Fp = 128; off = OFF3; break;
      default: w = w4; m = m4; Fm = 128; O = 2;   Fp = 128; off = OFF4; break;
    }

    float ss = 0.f;
    for (int f = 0; f < Fm; ++f) {
        float v = w[f * O + o] * m[(b * Fm + f) * O + o];
        ss += v * v;
    }
    float r = 1.0f / fmaxf(sqrtf(ss), 1e-12f);

    float* pT = ws + off + (b * O + o) * Fp;
    for (int f = 0; f < Fm; ++f) {
        float v = w[f * O + o] * m[(b * Fm + f) * O + o];
        pT[f] = v * r;
    }
    if (layer == 0) pT[35] = 0.f;           // zero-pad fan-in 35 -> 36
    ws[OFFB + layer * 512 + b * 128 + o] = w[Fm * O + o];   // bias row
}

// Accumulate NACC outputs over F inputs. hl: this lane's hidden row (LDS).
// pb: param rows base (wave-uniform -> s_load). bs: bias base (wave-uniform).
template<int F, int NACC>
__device__ __forceinline__ void layer_accum(const float* __restrict__ hl,
                                            const float* __restrict__ pb,
                                            const float* __restrict__ bs,
                                            float* acc)
{
    #pragma unroll
    for (int j = 0; j < NACC; ++j) acc[j] = bs[j];
    #pragma unroll 2
    for (int f = 0; f < F; f += 4) {
        float4 h4 = *(const float4*)(hl + f);   // ds_read_b128, conflict-free (stride 132)
        #pragma unroll
        for (int j = 0; j < NACC; ++j) {
            const float* pr = pb + j * F + f;   // uniform -> s_load_dwordx4
            acc[j] = fmaf(h4.x, pr[0], acc[j]);
            acc[j] = fmaf(h4.y, pr[1], acc[j]);
            acc[j] = fmaf(h4.z, pr[2], acc[j]);
            acc[j] = fmaf(h4.w, pr[3], acc[j]);
        }
    }
}

__global__ __launch_bounds__(512, 4)
void hyponet_main(const float* __restrict__ coord,
                  const float* __restrict__ lat,
                  const float* __restrict__ ws,
                  float* __restrict__ out)
{
    __shared__ float hs[64][132];   // 64 points x (128 feat + pad); 33792 B
    const int tid  = threadIdx.x;
    const int lane = tid & 63;
    const int wv   = tid >> 6;               // 8 waves: o-block owner
    const int b    = blockIdx.x >> 10;       // 1024 tiles per batch
    const int tile = blockIdx.x & 1023;
    const int pg   = tile * 64 + lane;       // point index in [0,65536)

    // ---- bilinear upsample 64x64x32 -> per-point 32 feats (+3 coord, +0 pad)
    {
        const int y = pg >> 8, x = pg & 255;
        const float sy = (y + 0.5f) * 0.25f - 0.5f;
        const float sx = (x + 0.5f) * 0.25f - 0.5f;
        const float fy = floorf(sy), fx = floorf(sx);
        const float ty = sy - fy, tx = sx - fx;
        int y0 = (int)fy, x0 = (int)fx;
        const int y1 = min(y0 + 1, 63); y0 = max(y0, 0);
        const int x1 = min(x0 + 1, 63); x0 = max(x0, 0);
        const int c0 = wv * 4;               // each wave fills 4 channels
        const float* base = lat + ((size_t)b << 17) + c0;   // b*64*64*32
        const float4 v00 = *(const float4*)(base + (y0 * 64 + x0) * 32);
        const float4 v01 = *(const float4*)(base + (y0 * 64 + x1) * 32);
        const float4 v10 = *(const float4*)(base + (y1 * 64 + x0) * 32);
        const float4 v11 = *(const float4*)(base + (y1 * 64 + x1) * 32);
        float4 r;
        const float w00 = (1.f - ty) * (1.f - tx), w01 = (1.f - ty) * tx;
        const float w10 = ty * (1.f - tx),         w11 = ty * tx;
        r.x = w00 * v00.x + w01 * v01.x + w10 * v10.x + w11 * v11.x;
        r.y = w00 * v00.y + w01 * v01.y + w10 * v10.y + w11 * v11.y;
        r.z = w00 * v00.z + w01 * v01.z + w10 * v10.z + w11 * v11.z;
        r.w = w00 * v00.w + w01 * v01.w + w10 * v10.w + w11 * v11.w;
        *(float4*)&hs[lane][c0] = r;
        if (wv == 0) {
            const float* cp = coord + ((size_t)b * 65536 + pg) * 3;
            hs[lane][32] = cp[0];
            hs[lane][33] = cp[1];
            hs[lane][34] = cp[2];
            hs[lane][35] = 0.f;
        }
    }
    __syncthreads();

    const int ob = __builtin_amdgcn_readfirstlane(wv * 16);  // force wave-uniform -> s_load
    const float* hl = &hs[lane][0];
    float acc[16];

    // ---- layer 0: 36 -> 128, sin
    {
        const float* pb = ws + OFF0 + (b * 128 + ob) * 36;
        const float* bs = ws + OFFB + 0 * 512 + b * 128 + ob;
        layer_accum<36, 16>(hl, pb, bs, acc);
        #pragma unroll
        for (int j = 0; j < 16; ++j) acc[j] = sinf(acc[j]);
        __syncthreads();
        #pragma unroll
        for (int j = 0; j < 16; j += 4)
            *(float4*)&hs[lane][ob + j] = make_float4(acc[j], acc[j+1], acc[j+2], acc[j+3]);
        __syncthreads();
    }

    // ---- layers 1..3: 129 -> 128, sin
    #pragma unroll 1
    for (int L = 1; L <= 3; ++L) {
        const int off = (L == 1) ? OFF1 : (L == 2) ? OFF2 : OFF3;
        const float* pb = ws + off + (b * 128 + ob) * 128;
        const float* bs = ws + OFFB + L * 512 + b * 128 + ob;
        layer_accum<128, 16>(hl, pb, bs, acc);
        #pragma unroll
        for (int j = 0; j < 16; ++j) acc[j] = sinf(acc[j]);
        __syncthreads();
        #pragma unroll
        for (int j = 0; j < 16; j += 4)
            *(float4*)&hs[lane][ob + j] = make_float4(acc[j], acc[j+1], acc[j+2], acc[j+3]);
        __syncthreads();
    }

    // ---- layer 4: 129 -> 2, linear; wave 0 only
    if (wv == 0) {
        const float* pb = ws + OFF4 + b * 2 * 128;
        const float* bs = ws + OFFB + 4 * 512 + b * 128;
        float a2[2];
        layer_accum<128, 2>(hl, pb, bs, a2);
        float2 o2; o2.x = a2[0]; o2.y = a2[1];
        *(float2*)&out[((size_t)b * 65536 + pg) * 2] = o2;
    }
}

extern "C" void kernel_launch(void* const* d_in, const int* in_sizes, int n_in,
                              void* d_out, int out_size, void* d_ws, size_t ws_size,
                              hipStream_t stream)
{
    const float* coord = (const float*)d_in[0];
    const float* lat   = (const float*)d_in[1];
    float* ws = (float*)d_ws;

    prep_params<<<9, 256, 0, stream>>>(
        (const float*)d_in[2], (const float*)d_in[3], (const float*)d_in[4],
        (const float*)d_in[5], (const float*)d_in[6],
        (const float*)d_in[7], (const float*)d_in[8], (const float*)d_in[9],
        (const float*)d_in[10], (const float*)d_in[11], ws);

    hyponet_main<<<4096, 512, 0, stream>>>(coord, lat, ws, (float*)d_out);
}

// Round 2
// 520.822 us; speedup vs baseline: 1.2904x; 1.2904x over previous
//
#include <hip/hip_runtime.h>
#include <math.h>

// Workspace layout (floats):
//  pT0 [4][128][36]   @ OFF0
//  pT1 [4][128][128]  @ OFF1
//  pT2 [4][128][128]  @ OFF2
//  pT3 [4][128][128]  @ OFF3
//  pT4 [4][2][128]    @ OFF4
//  bias[5][4][128]    @ OFFB   (layer-major; L4 uses o=0,1)
#define OFF0 0
#define OFF1 18432
#define OFF2 83968
#define OFF3 149504
#define OFF4 215040
#define OFFB 216064

__global__ void prep_params(
    const float* __restrict__ w0, const float* __restrict__ w1,
    const float* __restrict__ w2, const float* __restrict__ w3,
    const float* __restrict__ w4,
    const float* __restrict__ m0, const float* __restrict__ m1,
    const float* __restrict__ m2, const float* __restrict__ m3,
    const float* __restrict__ m4,
    float* __restrict__ ws)
{
    int idx = blockIdx.x * blockDim.x + threadIdx.x;
    if (idx >= 2056) return;
    int layer, b, o;
    if (idx < 2048) { layer = idx >> 9; b = (idx >> 7) & 3; o = idx & 127; }
    else { layer = 4; int r = idx - 2048; b = r >> 1; o = r & 1; }

    const float* w; const float* m; int Fm, O, Fp; int off;
    switch (layer) {
      case 0:  w = w0; m = m0; Fm = 35;  O = 128; Fp = 36;  off = OFF0; break;
      case 1:  w = w1; m = m1; Fm = 128; O = 128; Fp = 128; off = OFF1; break;
      case 2:  w = w2; m = m2; Fm = 128; O = 128; Fp = 128; off = OFF2; break;
      case 3:  w = w3; m = m3; Fm = 128; O = 128; Fp = 128; off = OFF3; break;
      default: w = w4; m = m4; Fm = 128; O = 2;   Fp = 128; off = OFF4; break;
    }

    float ss = 0.f;
    for (int f = 0; f < Fm; ++f) {
        float v = w[f * O + o] * m[(b * Fm + f) * O + o];
        ss += v * v;
    }
    float r = 1.0f / fmaxf(sqrtf(ss), 1e-12f);

    float* pT = ws + off + (b * O + o) * Fp;
    for (int f = 0; f < Fm; ++f) {
        float v = w[f * O + o] * m[(b * Fm + f) * O + o];
        pT[f] = v * r;
    }
    if (layer == 0) pT[35] = 0.f;           // zero-pad fan-in 35 -> 36
    ws[OFFB + layer * 512 + b * 128 + o] = w[Fm * O + o];   // bias row
}

// Accumulate NACC outputs over F inputs. hl: this lane's hidden row (LDS).
// pb: param rows base (wave-uniform -> s_load). bs: bias base (wave-uniform).
// NACC=8 keeps live s_load data at 32 SGPRs/f-quad so the compiler can
// software-pipeline a full f-quad of scalar loads ahead.
template<int F, int NACC>
__device__ __forceinline__ void layer_accum(const float* __restrict__ hl,
                                            const float* __restrict__ pb,
                                            const float* __restrict__ bs,
                                            float* acc)
{
    #pragma unroll
    for (int j = 0; j < NACC; ++j) acc[j] = bs[j];
    #pragma unroll 2
    for (int f = 0; f < F; f += 4) {
        float4 h4 = *(const float4*)(hl + f);   // ds_read_b128, conflict-free (stride 132)
        #pragma unroll
        for (int j = 0; j < NACC; ++j) {
            const float* pr = pb + j * F + f;   // uniform -> s_load_dwordx4
            acc[j] = fmaf(h4.x, pr[0], acc[j]);
            acc[j] = fmaf(h4.y, pr[1], acc[j]);
            acc[j] = fmaf(h4.z, pr[2], acc[j]);
            acc[j] = fmaf(h4.w, pr[3], acc[j]);
        }
    }
}

__global__ __launch_bounds__(512, 8)
void hyponet_main(const float* __restrict__ coord,
                  const float* __restrict__ lat,
                  const float* __restrict__ ws,
                  float* __restrict__ out)
{
    __shared__ float hs[64][132];   // 64 points x (128 feat + pad); 33792 B
    const int tid  = threadIdx.x;
    const int lane = tid & 63;
    const int wv   = tid >> 6;               // 8 waves: o-block owner
    const int b    = blockIdx.x >> 10;       // 1024 tiles per batch
    const int tile = blockIdx.x & 1023;
    const int pg   = tile * 64 + lane;       // point index in [0,65536)

    // ---- bilinear upsample 64x64x32 -> per-point 32 feats (+3 coord, +pad)
    {
        const int y = pg >> 8, x = pg & 255;
        const float sy = (y + 0.5f) * 0.25f - 0.5f;
        const float sx = (x + 0.5f) * 0.25f - 0.5f;
        const float fy = floorf(sy), fx = floorf(sx);
        const float ty = sy - fy, tx = sx - fx;
        int y0 = (int)fy, x0 = (int)fx;
        const int y1 = min(y0 + 1, 63); y0 = max(y0, 0);
        const int x1 = min(x0 + 1, 63); x0 = max(x0, 0);
        const int c0 = wv * 4;               // each wave fills 4 channels
        const float* base = lat + ((size_t)b << 17) + c0;   // b*64*64*32
        const float4 v00 = *(const float4*)(base + (y0 * 64 + x0) * 32);
        const float4 v01 = *(const float4*)(base + (y0 * 64 + x1) * 32);
        const float4 v10 = *(const float4*)(base + (y1 * 64 + x0) * 32);
        const float4 v11 = *(const float4*)(base + (y1 * 64 + x1) * 32);
        float4 r;
        const float w00 = (1.f - ty) * (1.f - tx), w01 = (1.f - ty) * tx;
        const float w10 = ty * (1.f - tx),         w11 = ty * tx;
        r.x = w00 * v00.x + w01 * v01.x + w10 * v10.x + w11 * v11.x;
        r.y = w00 * v00.y + w01 * v01.y + w10 * v10.y + w11 * v11.y;
        r.z = w00 * v00.z + w01 * v01.z + w10 * v10.z + w11 * v11.z;
        r.w = w00 * v00.w + w01 * v01.w + w10 * v10.w + w11 * v11.w;
        *(float4*)&hs[lane][c0] = r;
        if (wv == 0) {
            const float* cp = coord + ((size_t)b * 65536 + pg) * 3;
            hs[lane][32] = cp[0];
            hs[lane][33] = cp[1];
            hs[lane][34] = cp[2];
            hs[lane][35] = 0.f;
        }
    }
    __syncthreads();

    const float* hl = &hs[lane][0];
    float acc[16];

    // ---- layer 0: 36 -> 128, sin
    {
        const int ob0 = __builtin_amdgcn_readfirstlane(wv * 16);
        const int ob1 = __builtin_amdgcn_readfirstlane(wv * 16 + 8);
        layer_accum<36, 8>(hl, ws + OFF0 + (b * 128 + ob0) * 36,
                           ws + OFFB + b * 128 + ob0, acc);
        layer_accum<36, 8>(hl, ws + OFF0 + (b * 128 + ob1) * 36,
                           ws + OFFB + b * 128 + ob1, acc + 8);
        #pragma unroll
        for (int j = 0; j < 16; ++j) acc[j] = __sinf(acc[j]);
        __syncthreads();
        const int ob = wv * 16;
        #pragma unroll
        for (int j = 0; j < 16; j += 4)
            *(float4*)&hs[lane][ob + j] = make_float4(acc[j], acc[j+1], acc[j+2], acc[j+3]);
        __syncthreads();
    }

    // ---- layers 1..3: 129 -> 128, sin
    #pragma unroll 1
    for (int L = 1; L <= 3; ++L) {
        const int off = (L == 1) ? OFF1 : (L == 2) ? OFF2 : OFF3;
        const int ob0 = __builtin_amdgcn_readfirstlane(wv * 16);
        const int ob1 = __builtin_amdgcn_readfirstlane(wv * 16 + 8);
        layer_accum<128, 8>(hl, ws + off + (b * 128 + ob0) * 128,
                            ws + OFFB + L * 512 + b * 128 + ob0, acc);
        layer_accum<128, 8>(hl, ws + off + (b * 128 + ob1) * 128,
                            ws + OFFB + L * 512 + b * 128 + ob1, acc + 8);
        #pragma unroll
        for (int j = 0; j < 16; ++j) acc[j] = __sinf(acc[j]);
        __syncthreads();
        const int ob = wv * 16;
        #pragma unroll
        for (int j = 0; j < 16; j += 4)
            *(float4*)&hs[lane][ob + j] = make_float4(acc[j], acc[j+1], acc[j+2], acc[j+3]);
        __syncthreads();
    }

    // ---- layer 4: 129 -> 2, linear; wave 0 only
    if (wv == 0) {
        const float* pb = ws + OFF4 + b * 2 * 128;
        const float* bs = ws + OFFB + 4 * 512 + b * 128;
        float a2[2];
        layer_accum<128, 2>(hl, pb, bs, a2);
        float2 o2; o2.x = a2[0]; o2.y = a2[1];
        *(float2*)&out[((size_t)b * 65536 + pg) * 2] = o2;
    }
}

extern "C" void kernel_launch(void* const* d_in, const int* in_sizes, int n_in,
                              void* d_out, int out_size, void* d_ws, size_t ws_size,
                              hipStream_t stream)
{
    const float* coord = (const float*)d_in[0];
    const float* lat   = (const float*)d_in[1];
    float* ws = (float*)d_ws;

    prep_params<<<9, 256, 0, stream>>>(
        (const float*)d_in[2], (const float*)d_in[3], (const float*)d_in[4],
        (const float*)d_in[5], (const float*)d_in[6],
        (const float*)d_in[7], (const float*)d_in[8], (const float*)d_in[9],
        (const float*)d_in[10], (const float*)d_in[11], ws);

    hyponet_main<<<4096, 512, 0, stream>>>(coord, lat, ws, (float*)d_out);
}

// Round 7
// 520.308 us; speedup vs baseline: 1.2917x; 1.0010x over previous
//
#include <hip/hip_runtime.h>
#include <math.h>

// Workspace layout (floats):
//  pT0 [4][128][36]   @ OFF0
//  pT1 [4][128][128]  @ OFF1
//  pT2 [4][128][128]  @ OFF2
//  pT3 [4][128][128]  @ OFF3
//  pT4 [4][2][128]    @ OFF4
//  bias[5][4][128]    @ OFFB   (layer-major; L4 uses o=0,1)
#define OFF0 0
#define OFF1 18432
#define OFF2 83968
#define OFF3 149504
#define OFF4 215040
#define OFFB 216064

__global__ void prep_params(
    const float* __restrict__ w0, const float* __restrict__ w1,
    const float* __restrict__ w2, const float* __restrict__ w3,
    const float* __restrict__ w4,
    const float* __restrict__ m0, const float* __restrict__ m1,
    const float* __restrict__ m2, const float* __restrict__ m3,
    const float* __restrict__ m4,
    float* __restrict__ ws)
{
    int idx = blockIdx.x * blockDim.x + threadIdx.x;
    if (idx >= 2056) return;
    int layer, b, o;
    if (idx < 2048) { layer = idx >> 9; b = (idx >> 7) & 3; o = idx & 127; }
    else { layer = 4; int r = idx - 2048; b = r >> 1; o = r & 1; }

    const float* w; const float* m; int Fm, O, Fp; int off;
    switch (layer) {
      case 0:  w = w0; m = m0; Fm = 35;  O = 128; Fp = 36;  off = OFF0; break;
      case 1:  w = w1; m = m1; Fm = 128; O = 128; Fp = 128; off = OFF1; break;
      case 2:  w = w2; m = m2; Fm = 128; O = 128; Fp = 128; off = OFF2; break;
      case 3:  w = w3; m = m3; Fm = 128; O = 128; Fp = 128; off = OFF3; break;
      default: w = w4; m = m4; Fm = 128; O = 2;   Fp = 128; off = OFF4; break;
    }

    float ss = 0.f;
    for (int f = 0; f < Fm; ++f) {
        float v = w[f * O + o] * m[(b * Fm + f) * O + o];
        ss += v * v;
    }
    float r = 1.0f / fmaxf(sqrtf(ss), 1e-12f);

    float* pT = ws + off + (b * O + o) * Fp;
    for (int f = 0; f < Fm; ++f) {
        float v = w[f * O + o] * m[(b * Fm + f) * O + o];
        pT[f] = v * r;
    }
    if (layer == 0) pT[35] = 0.f;           // zero-pad fan-in 35 -> 36
    ws[OFFB + layer * 512 + b * 128 + o] = w[Fm * O + o];   // bias row
}

// Accumulate NACC outputs over F inputs. hl: this lane's hidden row (LDS).
// pb: param rows base (wave-uniform -> s_load). bs: bias base (wave-uniform).
// NACC=8 keeps live s_load data at 32 SGPRs/f-quad so the compiler can
// software-pipeline a full f-quad of scalar loads ahead.
template<int F, int NACC>
__device__ __forceinline__ void layer_accum(const float* __restrict__ hl,
                                            const float* __restrict__ pb,
                                            const float* __restrict__ bs,
                                            float* acc)
{
    #pragma unroll
    for (int j = 0; j < NACC; ++j) acc[j] = bs[j];
    #pragma unroll 2
    for (int f = 0; f < F; f += 4) {
        float4 h4 = *(const float4*)(hl + f);   // ds_read_b128, conflict-free (stride 132)
        #pragma unroll
        for (int j = 0; j < NACC; ++j) {
            const float* pr = pb + j * F + f;   // uniform -> s_load_dwordx4
            acc[j] = fmaf(h4.x, pr[0], acc[j]);
            acc[j] = fmaf(h4.y, pr[1], acc[j]);
            acc[j] = fmaf(h4.z, pr[2], acc[j]);
            acc[j] = fmaf(h4.w, pr[3], acc[j]);
        }
    }
}

__global__ __launch_bounds__(512, 8)
void hyponet_main(const float* __restrict__ coord,
                  const float* __restrict__ lat,
                  const float* __restrict__ ws,
                  float* __restrict__ out)
{
    __shared__ float hs[64][132];   // 64 points x (128 feat + pad); 33792 B
    const int tid  = threadIdx.x;
    const int lane = tid & 63;
    const int wv   = tid >> 6;               // 8 waves: o-block owner
    const int b    = blockIdx.x >> 10;       // 1024 tiles per batch
    const int tile = blockIdx.x & 1023;
    const int pg   = tile * 64 + lane;       // point index in [0,65536)

    // ---- bilinear upsample 64x64x32 -> per-point 32 feats (+3 coord, +pad)
    {
        const int y = pg >> 8, x = pg & 255;
        const float sy = (y + 0.5f) * 0.25f - 0.5f;
        const float sx = (x + 0.5f) * 0.25f - 0.5f;
        const float fy = floorf(sy), fx = floorf(sx);
        const float ty = sy - fy, tx = sx - fx;
        int y0 = (int)fy, x0 = (int)fx;
        const int y1 = min(y0 + 1, 63); y0 = max(y0, 0);
        const int x1 = min(x0 + 1, 63); x0 = max(x0, 0);
        const int c0 = wv * 4;               // each wave fills 4 channels
        const float* base = lat + ((size_t)b << 17) + c0;   // b*64*64*32
        const float4 v00 = *(const float4*)(base + (y0 * 64 + x0) * 32);
        const float4 v01 = *(const float4*)(base + (y0 * 64 + x1) * 32);
        const float4 v10 = *(const float4*)(base + (y1 * 64 + x0) * 32);
        const float4 v11 = *(const float4*)(base + (y1 * 64 + x1) * 32);
        float4 r;
        const float w00 = (1.f - ty) * (1.f - tx), w01 = (1.f - ty) * tx;
        const float w10 = ty * (1.f - tx),         w11 = ty * tx;
        r.x = w00 * v00.x + w01 * v01.x + w10 * v10.x + w11 * v11.x;
        r.y = w00 * v00.y + w01 * v01.y + w10 * v10.y + w11 * v11.y;
        r.z = w00 * v00.z + w01 * v01.z + w10 * v10.z + w11 * v11.z;
        r.w = w00 * v00.w + w01 * v01.w + w10 * v10.w + w11 * v11.w;
        *(float4*)&hs[lane][c0] = r;
        if (wv == 0) {
            const float* cp = coord + ((size_t)b * 65536 + pg) * 3;
            hs[lane][32] = cp[0];
            hs[lane][33] = cp[1];
            hs[lane][34] = cp[2];
            hs[lane][35] = 0.f;
        }
    }
    __syncthreads();

    const float* hl = &hs[lane][0];
    float acc[16];

    // ---- layer 0: 36 -> 128, sin
    {
        const int ob0 = __builtin_amdgcn_readfirstlane(wv * 16);
        const int ob1 = __builtin_amdgcn_readfirstlane(wv * 16 + 8);
        layer_accum<36, 8>(hl, ws + OFF0 + (b * 128 + ob0) * 36,
                           ws + OFFB + b * 128 + ob0, acc);
        layer_accum<36, 8>(hl, ws + OFF0 + (b * 128 + ob1) * 36,
                           ws + OFFB + b * 128 + ob1, acc + 8);
        #pragma unroll
        for (int j = 0; j < 16; ++j) acc[j] = __sinf(acc[j]);
        __syncthreads();
        const int ob = wv * 16;
        #pragma unroll
        for (int j = 0; j < 16; j += 4)
            *(float4*)&hs[lane][ob + j] = make_float4(acc[j], acc[j+1], acc[j+2], acc[j+3]);
        __syncthreads();
    }

    // ---- layers 1..3: 129 -> 128, sin
    #pragma unroll 1
    for (int L = 1; L <= 3; ++L) {
        const int off = (L == 1) ? OFF1 : (L == 2) ? OFF2 : OFF3;
        const int ob0 = __builtin_amdgcn_readfirstlane(wv * 16);
        const int ob1 = __builtin_amdgcn_readfirstlane(wv * 16 + 8);
        layer_accum<128, 8>(hl, ws + off + (b * 128 + ob0) * 128,
                            ws + OFFB + L * 512 + b * 128 + ob0, acc);
        layer_accum<128, 8>(hl, ws + off + (b * 128 + ob1) * 128,
                            ws + OFFB + L * 512 + b * 128 + ob1, acc + 8);
        #pragma unroll
        for (int j = 0; j < 16; ++j) acc[j] = __sinf(acc[j]);
        __syncthreads();
        const int ob = wv * 16;
        #pragma unroll
        for (int j = 0; j < 16; j += 4)
            *(float4*)&hs[lane][ob + j] = make_float4(acc[j], acc[j+1], acc[j+2], acc[j+3]);
        __syncthreads();
    }

    // ---- layer 4: 129 -> 2, linear; wave 0 only
    if (wv == 0) {
        const float* pb = ws + OFF4 + b * 2 * 128;
        const float* bs = ws + OFFB + 4 * 512 + b * 128;
        float a2[2];
        layer_accum<128, 2>(hl, pb, bs, a2);
        float2 o2; o2.x = a2[0]; o2.y = a2[1];
        *(float2*)&out[((size_t)b * 65536 + pg) * 2] = o2;
    }
}

extern "C" void kernel_launch(void* const* d_in, const int* in_sizes, int n_in,
                              void* d_out, int out_size, void* d_ws, size_t ws_size,
                              hipStream_t stream)
{
    const float* coord = (const float*)d_in[0];
    const float* lat   = (const float*)d_in[1];
    float* ws = (float*)d_ws;

    prep_params<<<9, 256, 0, stream>>>(
        (const float*)d_in[2], (const float*)d_in[3], (const float*)d_in[4],
        (const float*)d_in[5], (const float*)d_in[6],
        (const float*)d_in[7], (const float*)d_in[8], (const float*)d_in[9],
        (const float*)d_in[10], (const float*)d_in[11], ws);

    hyponet_main<<<4096, 512, 0, stream>>>(coord, lat, ws, (float*)d_out);
}